// Round 6
// baseline (2242.352 us; speedup 1.0000x reference)
//
#include <hip/hip_runtime.h>
#include <hip/hip_bf16.h>

// BiLSTM: B=64, T=2048, F=128, U=128. fp32 in/out.
// Phase 1: zx[d][bg][t][g][nt][m][lm] (f16) = scale_g * (x@Wx + b'), with
//          per-gate scale {-K, 2K, -K, -K}, K = log2(e), forget bias folded.
// Phase 2: 16 WGs (one per batch-group), 8 waves: waves 0-3 = forward chain,
//          waves 4-7 = backward chain (independent recurrences). Each SIMD
//          gets 1 fw + 1 bw wave -> the partner's issue hides the other's
//          dependency stalls while doubling per-CU throughput. Each chain
//          uses the 4-wave/2-cell shape (halved LDS reads: 16 b128/chain).
//          h stride 144 (verified 0 conflicts), exp2-prescaled gates, zc in
//          MFMA C operand, t-loop unrolled x2, lgkm-only barrier.

typedef _Float16 half8_t __attribute__((ext_vector_type(8)));
typedef _Float16 half4_t __attribute__((ext_vector_type(4)));
typedef float floatx4 __attribute__((ext_vector_type(4)));

#define T_SEQ 2048
#define GDIM 512
#define KLOG2E 1.4426950408889634f

__device__ __forceinline__ float exp2_f(float x) {
#if __has_builtin(__builtin_amdgcn_exp2f)
    return __builtin_amdgcn_exp2f(x);
#else
    return __expf(x * 0.6931471805599453f);
#endif
}
// sigmoid with pre-negated/scaled arg: x' = -K*x  =>  s = 1/(1+2^x')
__device__ __forceinline__ float sigm2(float x) {
    return __builtin_amdgcn_rcpf(1.0f + exp2_f(x));
}
// tanh with pre-scaled arg: x' = 2K*x  =>  t = 1 - 2/(1+2^x')
__device__ __forceinline__ float tanh2(float x) {
    return 1.0f - 2.0f * __builtin_amdgcn_rcpf(1.0f + exp2_f(x));
}
__device__ __forceinline__ float sel4(floatx4 v, int m) {
    float a = (m & 1) ? v[1] : v[0];
    float b = (m & 1) ? v[3] : v[2];
    return (m & 2) ? b : a;
}

// ---------------- Phase 1: Zx GEMM (identical to round-4, verified) --------
// grid: (32 ttiles, 64 batches, 2 dirs), block 256. A staged once; 4 ctile passes.
__global__ __launch_bounds__(256) void zx_gemm(
    const float* __restrict__ x,
    const float* __restrict__ Wfw, const float* __restrict__ bfw,
    const float* __restrict__ Wbw, const float* __restrict__ bbw,
    _Float16* __restrict__ zx) {
    const int tid = threadIdx.x;
    const int tt = blockIdx.x;           // 0..31
    const int b = blockIdx.y;            // batch
    const int d = blockIdx.z;            // dir
    const int t0 = tt * 64;
    const float* W = d ? Wbw : Wfw;
    const float* bias = d ? bbw : bfw;
    const int bg = b >> 2, m = b & 3;

    __shared__ _Float16 lA[64 * 136];
    __shared__ _Float16 lB[128 * 136];

    // stage A = x[b, t0..t0+63, 0..127] -> lA[row][k]
    const float* xp = x + ((size_t)b * T_SEQ + t0) * 128;
    for (int i = 0; i < 8; ++i) {
        int v = i * 256 + tid;
        int r = v >> 5;
        int kq = (v & 31) << 2;
        float4 f = *(const float4*)(xp + r * 128 + kq);
        half4_t h4;
        h4[0] = (_Float16)f.x; h4[1] = (_Float16)f.y;
        h4[2] = (_Float16)f.z; h4[3] = (_Float16)f.w;
        *(half4_t*)&lA[r * 136 + kq] = h4;
    }

    const int w1 = tid >> 6, lane = tid & 63, lm = lane & 15, q = lane >> 4;

    for (int ct = 0; ct < 4; ++ct) {
        // stage B = W[0..127, ct*128 .. +128) transposed -> lB[col][k]
        const float* wp = W + ct * 128;
        for (int i = 0; i < 16; ++i) {
            int v = i * 256 + tid;
            int k = v >> 5;
            int cq = (v & 31) << 2;
            float4 f = *(const float4*)(wp + (size_t)k * GDIM + cq);
            lB[(cq + 0) * 136 + k] = (_Float16)f.x;
            lB[(cq + 1) * 136 + k] = (_Float16)f.y;
            lB[(cq + 2) * 136 + k] = (_Float16)f.z;
            lB[(cq + 3) * 136 + k] = (_Float16)f.w;
        }
        __syncthreads();

        floatx4 acc[8];
#pragma unroll
        for (int nt = 0; nt < 8; ++nt) acc[nt] = (floatx4){0.f, 0.f, 0.f, 0.f};
#pragma unroll
        for (int ks = 0; ks < 4; ++ks) {
            const int k0 = ks * 32 + q * 8;
            half8_t a = *(const half8_t*)&lA[(w1 * 16 + lm) * 136 + k0];
#pragma unroll
            for (int nt = 0; nt < 8; ++nt) {
                half8_t bf = *(const half8_t*)&lB[(nt * 16 + lm) * 136 + k0];
                acc[nt] = __builtin_amdgcn_mfma_f32_16x16x32_f16(a, bf, acc[nt], 0, 0, 0);
            }
        }
        // store scaled: g = ct; scale i/f/o = -K, j = +2K; forget bias folded.
        const float sc = (ct == 1) ? (2.0f * KLOG2E) : (-KLOG2E);
        const float badd = (ct == 2) ? 1.0f : 0.0f;
#pragma unroll
        for (int nt = 0; nt < 8; ++nt) {
            float bv = bias[ct * 128 + nt * 16 + lm] + badd;
#pragma unroll
            for (int rr = 0; rr < 4; ++rr) {
                int t = t0 + w1 * 16 + q * 4 + rr;
                size_t oi = (((size_t)(d * 16 + bg) * T_SEQ + t) * 4 + ct) * 512
                            + nt * 64 + m * 16 + lm;
                zx[oi] = (_Float16)(sc * (acc[nt][rr] + bv));
            }
        }
        __syncthreads();   // before restaging lB
    }
}

// ---------------- Phase 2: recurrence ----------------
// grid: (16 batch-groups), block 512 = 8 waves.
// Waves 0-3: d=0 chain; waves 4-7: d=1 chain. Within a chain, wave wd owns
// units wd*32 + c*16 + lm (c=0,1), batch = q. 2 cells/lane.
__global__ __launch_bounds__(512, 2) void lstm_rec(
    const float* __restrict__ Wfw, const float* __restrict__ Wbw,
    const _Float16* __restrict__ zx, float* __restrict__ out) {
    const int bg = blockIdx.x;            // 0..15
    const int b0 = bg * 4;
    const int tid = threadIdx.x;
    const int w8 = tid >> 6;              // 0..7
    const int d = w8 >> 2;                // 0 = fw, 1 = bw
    const int wd = w8 & 3;                // wave within chain
    const int lane = tid & 63, lm = lane & 15, q = lane >> 4;
    const float* Wd = d ? Wbw : Wfw;

    __shared__ _Float16 hbuf[2][2][4 * 144]; // [dir][parity][row(batch)*144+unit]
                                             // stride 144: af reads worst-case
                                             // 2-way (free); r4 measured 0 confl.

    // Wh B-fragments: bfr[g][c][ks], col = g*128 + wd*32 + c*16 + lm,
    // k = 128 + ks*32 + q*8 + j. Pre-scaled by per-gate exp2 factor.
    half8_t bfr[4][2][4];
#pragma unroll
    for (int g = 0; g < 4; ++g) {
        const float sc = (g == 1) ? (2.0f * KLOG2E) : (-KLOG2E);
#pragma unroll
        for (int c = 0; c < 2; ++c)
#pragma unroll
            for (int ks = 0; ks < 4; ++ks) {
                int col = g * 128 + wd * 32 + c * 16 + lm;
                int kb = 128 + ks * 32 + q * 8;
                half8_t f;
#pragma unroll
                for (int j = 0; j < 8; ++j)
                    f[j] = (_Float16)(sc * Wd[(size_t)(kb + j) * GDIM + col]);
                bfr[g][c][ks] = f;
            }
    }

    for (int i = tid; i < 2 * 2 * 4 * 144; i += 512) ((_Float16*)hbuf)[i] = (_Float16)0.f;

    // zx addressing: zx_d wave-uniform base, zoff loop-invariant lane offset.
    const _Float16* zx_d = zx + (size_t)(d * 16 + bg) * T_SEQ * 2048;
    const unsigned zoff = (unsigned)(wd * 128 + lane);
    // out addressing: per-step uniform row (t*256) + per-lane u32 base.
    const unsigned obase = (unsigned)((b0 + q) * T_SEQ) * 256u
                           + (unsigned)(d * 128 + wd * 32 + lm);

    // prefetch depth 2: na for step s, nb for step s+1 (8 = 4 gates x 2 ctiles)
    _Float16 na[8], nb[8];
    {
        const _Float16* r0 = zx_d + (size_t)(d ? (T_SEQ - 1) : 0) * 2048;
        const _Float16* r1 = zx_d + (size_t)(d ? (T_SEQ - 2) : 1) * 2048;
#pragma unroll
        for (int g = 0; g < 4; ++g)
#pragma unroll
            for (int c = 0; c < 2; ++c) {
                na[g * 2 + c] = r0[zoff + g * 512 + c * 64];
                nb[g * 2 + c] = r1[zoff + g * 512 + c * 64];
            }
    }
    float cst0 = 0.f, cst1 = 0.f;
    __syncthreads();

#define REC_STEP(RD, WR, NREG, SCUR)                                          \
    {                                                                         \
        const int t_ = d ? (T_SEQ - 1 - (SCUR)) : (SCUR);                     \
        half8_t af[4];                                                        \
        _Pragma("unroll")                                                     \
        for (int ks = 0; ks < 4; ++ks)                                        \
            af[ks] = *(const half8_t*)&hbuf[d][RD][(lm & 3) * 144 + ks * 32 + q * 8]; \
        float zc[8];                                                          \
        _Pragma("unroll")                                                     \
        for (int i = 0; i < 8; ++i) zc[i] = (float)NREG[i];                   \
        int sn_ = (SCUR) + 2; if (sn_ > T_SEQ - 1) sn_ = T_SEQ - 1;           \
        const int tn_ = d ? (T_SEQ - 1 - sn_) : sn_;                          \
        const _Float16* zrow_ = zx_d + (size_t)tn_ * 2048;                    \
        _Pragma("unroll")                                                     \
        for (int g = 0; g < 4; ++g)                                           \
            _Pragma("unroll")                                                 \
            for (int c = 0; c < 2; ++c)                                       \
                NREG[g * 2 + c] = zrow_[zoff + g * 512 + c * 64];             \
        floatx4 acg[4][2];                                                    \
        _Pragma("unroll")                                                     \
        for (int g = 0; g < 4; ++g)                                           \
            _Pragma("unroll")                                                 \
            for (int c = 0; c < 2; ++c) {                                     \
                float v_ = zc[g * 2 + c];                                     \
                acg[g][c] = (floatx4){v_, v_, v_, v_};                        \
            }                                                                 \
        _Pragma("unroll")                                                     \
        for (int ks = 0; ks < 4; ++ks)                                        \
            _Pragma("unroll")                                                 \
            for (int g = 0; g < 4; ++g) {                                     \
                acg[g][0] = __builtin_amdgcn_mfma_f32_16x16x32_f16(af[ks], bfr[g][0][ks], acg[g][0], 0, 0, 0); \
                acg[g][1] = __builtin_amdgcn_mfma_f32_16x16x32_f16(af[ks], bfr[g][1][ks], acg[g][1], 0, 0, 0); \
            }                                                                 \
        float zi0 = sel4(acg[0][0], q), zi1 = sel4(acg[0][1], q);             \
        float zj0 = sel4(acg[1][0], q), zj1 = sel4(acg[1][1], q);             \
        float zf0 = sel4(acg[2][0], q), zf1 = sel4(acg[2][1], q);             \
        float zo0 = sel4(acg[3][0], q), zo1 = sel4(acg[3][1], q);             \
        cst0 = cst0 * sigm2(zf0) + sigm2(zi0) * tanh2(zj0);                   \
        cst1 = cst1 * sigm2(zf1) + sigm2(zi1) * tanh2(zj1);                   \
        float h0_ = sigm2(zo0) * tanh2(2.0f * KLOG2E * cst0);                 \
        float h1_ = sigm2(zo1) * tanh2(2.0f * KLOG2E * cst1);                 \
        hbuf[d][WR][q * 144 + wd * 32 + lm] = (_Float16)h0_;                  \
        hbuf[d][WR][q * 144 + wd * 32 + 16 + lm] = (_Float16)h1_;             \
        float* orow_ = out + (size_t)t_ * 256;                                \
        orow_[obase] = h0_;                                                   \
        orow_[obase + 16] = h1_;                                              \
        __builtin_amdgcn_sched_barrier(0);                                    \
        asm volatile("s_waitcnt lgkmcnt(0)");                                 \
        __builtin_amdgcn_s_barrier();                                         \
        __builtin_amdgcn_sched_barrier(0);                                    \
    }

    for (int s = 0; s < T_SEQ; s += 2) {
        REC_STEP(0, 1, na, s);
        REC_STEP(1, 0, nb, s + 1);
    }
#undef REC_STEP
}

extern "C" void kernel_launch(void* const* d_in, const int* in_sizes, int n_in,
                              void* d_out, int out_size, void* d_ws, size_t ws_size,
                              hipStream_t stream) {
    const float* x   = (const float*)d_in[0];
    const float* Wfw = (const float*)d_in[1];
    const float* bfw = (const float*)d_in[2];
    const float* Wbw = (const float*)d_in[3];
    const float* bbw = (const float*)d_in[4];
    float* out = (float*)d_out;
    _Float16* zx = (_Float16*)d_ws;  // 2*16*2048*2048*2B = 256 MiB

    dim3 g1(32, 64, 2);
    zx_gemm<<<g1, 256, 0, stream>>>(x, Wfw, bfw, Wbw, bbw, zx);
    dim3 g2(16, 1);
    lstm_rec<<<g2, 512, 0, stream>>>(Wfw, Wbw, zx, out);
}

// Round 7
// 1455.098 us; speedup vs baseline: 1.5410x; 1.5410x over previous
//
#include <hip/hip_runtime.h>
#include <hip/hip_bf16.h>

// BiLSTM: B=64, T=2048, F=128, U=128. fp32 in/out.
// Phase 1 (zx_gemm2): zx[d][bg][t][g][nt][m][lm] (f16) = scale_g*(x@Wx + b'),
//   per-gate scale {-K, 2K, -K, -K}, K = log2(e), forget bias folded.
//   LDS-FREE: W^T fragments register-resident (loaded once, scale prefolded),
//   x fragments loaded per-lane from global (sector-coalesced) + converted
//   in-reg. No barriers, no transposes, no bank conflicts. 2-deep prefetch
//   via unroll-x2 ping-pong.
// Phase 2 (lstm_rec): EXACT round-5 kernel (verified 1039 us): 32 WGs
//   (2 dir x 16 bg), 8 waves (2/SIMD), 1 cell/lane, stride-144 h (0 confl),
//   exp2-prescaled gates, SGPR zx addressing, unroll x2, lgkm-only barrier.

typedef _Float16 half8_t __attribute__((ext_vector_type(8)));
typedef float floatx4 __attribute__((ext_vector_type(4)));

#define T_SEQ 2048
#define GDIM 512
#define KLOG2E 1.4426950408889634f

__device__ __forceinline__ float exp2_f(float x) {
#if __has_builtin(__builtin_amdgcn_exp2f)
    return __builtin_amdgcn_exp2f(x);
#else
    return __expf(x * 0.6931471805599453f);
#endif
}
// sigmoid with pre-negated/scaled arg: x' = -K*x  =>  s = 1/(1+2^x')
__device__ __forceinline__ float sigm2(float x) {
    return __builtin_amdgcn_rcpf(1.0f + exp2_f(x));
}
// tanh with pre-scaled arg: x' = 2K*x  =>  t = 1 - 2/(1+2^x')
__device__ __forceinline__ float tanh2(float x) {
    return 1.0f - 2.0f * __builtin_amdgcn_rcpf(1.0f + exp2_f(x));
}
__device__ __forceinline__ float sel4(floatx4 v, int m) {
    float a = (m & 1) ? v[1] : v[0];
    float b = (m & 1) ? v[3] : v[2];
    return (m & 2) ? b : a;
}

// ---------------- Phase 1: Zx GEMM, register-resident B, no LDS ------------
// grid: (4 ctiles, 64 batches, 2 dirs), block 512 (8 waves). Wave w owns
// t-rows w*16+lm of each 128-row tile; 16 tiles cover T=2048.
__global__ __launch_bounds__(512, 2) void zx_gemm2(
    const float* __restrict__ x,
    const float* __restrict__ Wfw, const float* __restrict__ bfw,
    const float* __restrict__ Wbw, const float* __restrict__ bbw,
    _Float16* __restrict__ zx) {
    const int ct = blockIdx.x;            // 0..3 gate (128-col chunk)
    const int b = blockIdx.y;             // batch
    const int d = blockIdx.z;             // dir
    const float* W = d ? Wbw : Wfw;
    const float* bias = d ? bbw : bfw;
    const int bg = b >> 2, m = b & 3;
    const int tid = threadIdx.x;
    const int w = tid >> 6, lane = tid & 63, lm = lane & 15, q = lane >> 4;
    const float sc = (ct == 1) ? (2.0f * KLOG2E) : (-KLOG2E);
    const float badd = (ct == 2) ? 1.0f : 0.0f;

    // B-fragments: bfr[fc][ks], col = ct*128 + fc*16 + lm, k = ks*32+q*8+j.
    // Scale prefolded. Loads coalesced per instr (lm = consecutive dwords).
    half8_t bfr[8][4];
#pragma unroll
    for (int fc = 0; fc < 8; ++fc)
#pragma unroll
        for (int ks = 0; ks < 4; ++ks) {
            const int col = ct * 128 + fc * 16 + lm;
            const int kb = ks * 32 + q * 8;
            half8_t f;
#pragma unroll
            for (int j = 0; j < 8; ++j)
                f[j] = (_Float16)(sc * W[(size_t)(kb + j) * GDIM + col]);
            bfr[fc][ks] = f;
        }
    float sb[8];
#pragma unroll
    for (int fc = 0; fc < 8; ++fc)
        sb[fc] = sc * (bias[ct * 128 + fc * 16 + lm] + badd);

    // per-lane x source: row = w*16+lm (within tile), k-slot q*8. Per tile the
    // wave reads 16 rows x 4 ks-quarters x 32B = full sectors (coalesced).
    const float* xp = x + ((size_t)b * T_SEQ + w * 16 + lm) * 128 + q * 8;
    // zx dest: t = tt*128 + w*16 + q*4 + rr; col = ct*128 + fc*16 + lm
    _Float16* zb = zx + (((size_t)(d * 16 + bg) * T_SEQ + w * 16 + q * 4) * 4 + ct) * 512
                   + m * 16 + lm;

    float4 pa[8], pb[8];                  // ping-pong f32 fragments (2 tiles)
#pragma unroll
    for (int ks = 0; ks < 4; ++ks) {
        pa[ks * 2]     = *(const float4*)(xp + ks * 32);
        pa[ks * 2 + 1] = *(const float4*)(xp + ks * 32 + 4);
    }

#define ZX_TILE(CUR, NXT, TT)                                                 \
    {                                                                         \
        if ((TT) < 15) {                                                      \
            const float* xn_ = xp + (size_t)((TT) + 1) * 128 * 128;           \
            _Pragma("unroll")                                                 \
            for (int ks = 0; ks < 4; ++ks) {                                  \
                NXT[ks * 2]     = *(const float4*)(xn_ + ks * 32);            \
                NXT[ks * 2 + 1] = *(const float4*)(xn_ + ks * 32 + 4);        \
            }                                                                 \
        }                                                                     \
        half8_t af[4];                                                        \
        _Pragma("unroll")                                                     \
        for (int ks = 0; ks < 4; ++ks) {                                      \
            float4 a_ = CUR[ks * 2], b_ = CUR[ks * 2 + 1];                    \
            half8_t f_;                                                       \
            f_[0] = (_Float16)a_.x; f_[1] = (_Float16)a_.y;                   \
            f_[2] = (_Float16)a_.z; f_[3] = (_Float16)a_.w;                   \
            f_[4] = (_Float16)b_.x; f_[5] = (_Float16)b_.y;                   \
            f_[6] = (_Float16)b_.z; f_[7] = (_Float16)b_.w;                   \
            af[ks] = f_;                                                      \
        }                                                                     \
        floatx4 acc[8];                                                       \
        _Pragma("unroll")                                                     \
        for (int fc = 0; fc < 8; ++fc)                                        \
            acc[fc] = (floatx4){sb[fc], sb[fc], sb[fc], sb[fc]};              \
        _Pragma("unroll")                                                     \
        for (int ks = 0; ks < 4; ++ks)                                        \
            _Pragma("unroll")                                                 \
            for (int fc = 0; fc < 8; ++fc)                                    \
                acc[fc] = __builtin_amdgcn_mfma_f32_16x16x32_f16(af[ks], bfr[fc][ks], acc[fc], 0, 0, 0); \
        _Float16* zr_ = zb + (size_t)(TT) * 128 * 4 * 512;                    \
        _Pragma("unroll")                                                     \
        for (int fc = 0; fc < 8; ++fc)                                        \
            _Pragma("unroll")                                                 \
            for (int rr = 0; rr < 4; ++rr)                                    \
                zr_[(size_t)rr * 2048 + fc * 64] = (_Float16)acc[fc][rr];     \
    }

    for (int tt = 0; tt < 16; tt += 2) {
        ZX_TILE(pa, pb, tt);
        ZX_TILE(pb, pa, tt + 1);
    }
#undef ZX_TILE
}

// ---------------- Phase 2: recurrence (EXACT round-5 kernel) ----------------
// grid: (16 batch-groups, 2 dirs), block 512 (8 waves, 2/SIMD).
// Wave w owns cols {g*128 + w*16 + lm}, g=0..3; batch = q. 1 cell/lane.
__global__ __launch_bounds__(512) void lstm_rec(
    const float* __restrict__ Wfw, const float* __restrict__ Wbw,
    const _Float16* __restrict__ zx, float* __restrict__ out) {
    const int bg = blockIdx.x;            // 0..15
    const int d = blockIdx.y;             // 0..1
    const int b0 = bg * 4;
    const float* Wd = d ? Wbw : Wfw;
    const int tid = threadIdx.x;
    const int w = tid >> 6, lane = tid & 63, lm = lane & 15, q = lane >> 4;
    const int m = q;                      // batch slot of this lane's cell
    const int u = w * 16 + lm;            // unit 0..127

    __shared__ _Float16 hbuf[2][4 * 144]; // h rows (batch 0..3), stride 144 f16:
                                          // af read pattern is worst-case 2-way
                                          // (free); measured 0 conflicts in r4.

    // Wh B-fragments: bfr[g][ks], col = g*128 + u, k = 128 + ks*32 + q*8 + j.
    // Pre-scaled by per-gate exp2 factor {-K, 2K, -K, -K}.
    half8_t bfr[4][4];
#pragma unroll
    for (int g = 0; g < 4; ++g) {
        const float sc = (g == 1) ? (2.0f * KLOG2E) : (-KLOG2E);
#pragma unroll
        for (int ks = 0; ks < 4; ++ks) {
            int col = g * 128 + u;
            int kb = 128 + ks * 32 + q * 8;
            half8_t f;
#pragma unroll
            for (int j = 0; j < 8; ++j)
                f[j] = (_Float16)(sc * Wd[(size_t)(kb + j) * GDIM + col]);
            bfr[g][ks] = f;
        }
    }

    for (int i = tid; i < 2 * 4 * 144; i += 512) ((_Float16*)hbuf)[i] = (_Float16)0.f;

    // zx addressing: zx_d is WAVE-UNIFORM (SGPR base); zoff is a loop-invariant
    // 32-bit per-lane element offset -> saddr-form loads, ~zero per-step VALU.
    const _Float16* zx_d = zx + (size_t)(d * 16 + bg) * T_SEQ * 2048;
    const unsigned zoff = (unsigned)(w * 64 + lane);
    // out addressing: orow = out + t*256 is uniform; obase is per-lane u32.
    const unsigned obase = (unsigned)((b0 + m) * T_SEQ) * 256u + (unsigned)(d * 128 + u);

    // prefetch depth 2, registers na (for step s), nb (for step s+1)
    _Float16 na[4], nb[4];
    {
        const _Float16* r0 = zx_d + (size_t)(d ? (T_SEQ - 1) : 0) * 2048;
        const _Float16* r1 = zx_d + (size_t)(d ? (T_SEQ - 2) : 1) * 2048;
#pragma unroll
        for (int g = 0; g < 4; ++g) na[g] = r0[zoff + g * 512];
#pragma unroll
        for (int g = 0; g < 4; ++g) nb[g] = r1[zoff + g * 512];
    }
    float cst = 0.f;
    __syncthreads();

#define REC_STEP(RD, WR, NREG, SCUR)                                          \
    {                                                                         \
        const int t_ = d ? (T_SEQ - 1 - (SCUR)) : (SCUR);                     \
        half8_t af[4];                                                        \
        _Pragma("unroll")                                                     \
        for (int ks = 0; ks < 4; ++ks)                                        \
            af[ks] = *(const half8_t*)&hbuf[RD][(lm & 3) * 144 + ks * 32 + q * 8]; \
        float zc[4];                                                          \
        _Pragma("unroll")                                                     \
        for (int g = 0; g < 4; ++g) zc[g] = (float)NREG[g];                   \
        int sn_ = (SCUR) + 2; if (sn_ > T_SEQ - 1) sn_ = T_SEQ - 1;           \
        const int tn_ = d ? (T_SEQ - 1 - sn_) : sn_;                          \
        const _Float16* zrow_ = zx_d + (size_t)tn_ * 2048;                    \
        _Pragma("unroll")                                                     \
        for (int g = 0; g < 4; ++g) NREG[g] = zrow_[zoff + g * 512];          \
        floatx4 acg[4];                                                       \
        _Pragma("unroll")                                                     \
        for (int g = 0; g < 4; ++g) acg[g] = (floatx4){0.f, 0.f, 0.f, 0.f};   \
        _Pragma("unroll")                                                     \
        for (int ks = 0; ks < 4; ++ks)                                        \
            _Pragma("unroll")                                                 \
            for (int g = 0; g < 4; ++g)                                       \
                acg[g] = __builtin_amdgcn_mfma_f32_16x16x32_f16(af[ks], bfr[g][ks], acg[g], 0, 0, 0); \
        float zi = sel4(acg[0], m) + zc[0];                                   \
        float zj = sel4(acg[1], m) + zc[1];                                   \
        float zf = sel4(acg[2], m) + zc[2];                                   \
        float zo = sel4(acg[3], m) + zc[3];                                   \
        cst = cst * sigm2(zf) + sigm2(zi) * tanh2(zj);                        \
        float hv = sigm2(zo) * tanh2(2.0f * KLOG2E * cst);                    \
        hbuf[WR][m * 144 + u] = (_Float16)hv;                                 \
        float* orow_ = out + (size_t)t_ * 256;                                \
        orow_[obase] = hv;                                                    \
        __builtin_amdgcn_sched_barrier(0);                                    \
        asm volatile("s_waitcnt lgkmcnt(0)");                                 \
        __builtin_amdgcn_s_barrier();                                         \
        __builtin_amdgcn_sched_barrier(0);                                    \
    }

    for (int s = 0; s < T_SEQ; s += 2) {
        REC_STEP(0, 1, na, s);
        REC_STEP(1, 0, nb, s + 1);
    }
#undef REC_STEP
}

extern "C" void kernel_launch(void* const* d_in, const int* in_sizes, int n_in,
                              void* d_out, int out_size, void* d_ws, size_t ws_size,
                              hipStream_t stream) {
    const float* x   = (const float*)d_in[0];
    const float* Wfw = (const float*)d_in[1];
    const float* bfw = (const float*)d_in[2];
    const float* Wbw = (const float*)d_in[3];
    const float* bbw = (const float*)d_in[4];
    float* out = (float*)d_out;
    _Float16* zx = (_Float16*)d_ws;  // 2*16*2048*2048*2B = 256 MiB

    dim3 g1(4, 64, 2);
    zx_gemm2<<<g1, 512, 0, stream>>>(x, Wfw, bfw, Wbw, bbw, zx);
    dim3 g2(16, 2);
    lstm_rec<<<g2, 512, 0, stream>>>(Wfw, Wbw, zx, out);
}

// Round 8
// 1260.069 us; speedup vs baseline: 1.7795x; 1.1548x over previous
//
#include <hip/hip_runtime.h>
#include <hip/hip_bf16.h>

// BiLSTM: B=64, T=2048, F=128, U=128. fp32 in/out. SINGLE FUSED KERNEL.
// 32 WGs (2 dir x 16 batch-groups of 4), 8 waves (2/SIMD - verified best),
// 1 cell/lane (batch q, unit u = w*16+lm).
// Every 4 steps, an "x-burst": 16 MFMAs (4 gates x 4 K-slots) with A-rows
// mapped row = batch*4 + t_off compute zx for the next 4 timesteps; the C/D
// layout (row = q*4+reg) drops each lane's own-cell zx for steps s..s+3
// into zcs[g][reg] - no cross-lane exchange. Wx/Wh fragments both
// register-resident with per-gate exp2 scales {-K, 2K, -K, -K} prefolded;
// bias (+forget bias) prefolded into the burst C-init. No zx workspace,
// no second kernel. h stride 144 (verified 0 conflicts), lgkm-only barrier
// (no "memory" clobber) keeps x prefetch + out stores in flight.

typedef _Float16 half8_t __attribute__((ext_vector_type(8)));
typedef float floatx4 __attribute__((ext_vector_type(4)));

#define T_SEQ 2048
#define GDIM 512
#define KLOG2E 1.4426950408889634f

__device__ __forceinline__ float exp2_f(float x) {
#if __has_builtin(__builtin_amdgcn_exp2f)
    return __builtin_amdgcn_exp2f(x);
#else
    return __expf(x * 0.6931471805599453f);
#endif
}
// sigmoid with pre-negated/scaled arg: x' = -K*x  =>  s = 1/(1+2^x')
__device__ __forceinline__ float sigm2(float x) {
    return __builtin_amdgcn_rcpf(1.0f + exp2_f(x));
}
// tanh with pre-scaled arg: x' = 2K*x  =>  t = 1 - 2/(1+2^x')
__device__ __forceinline__ float tanh2(float x) {
    return 1.0f - 2.0f * __builtin_amdgcn_rcpf(1.0f + exp2_f(x));
}
__device__ __forceinline__ float sel4(floatx4 v, int m) {
    float a = (m & 1) ? v[1] : v[0];
    float b = (m & 1) ? v[3] : v[2];
    return (m & 2) ? b : a;
}

// grid: (16 batch-groups, 2 dirs), block 512 (8 waves, 2/SIMD).
__global__ __launch_bounds__(512, 2) void lstm_fused(
    const float* __restrict__ x,
    const float* __restrict__ Wfw, const float* __restrict__ bfw,
    const float* __restrict__ Wbw, const float* __restrict__ bbw,
    float* __restrict__ out) {
    const int bg = blockIdx.x;            // 0..15
    const int d = blockIdx.y;             // 0..1
    const int b0 = bg * 4;
    const float* Wd = d ? Wbw : Wfw;
    const float* bd = d ? bbw : bfw;
    const int tid = threadIdx.x;
    const int w = tid >> 6, lane = tid & 63, lm = lane & 15, q = lane >> 4;
    const int u = w * 16 + lm;            // unit 0..127; cell = (batch q, unit u)

    __shared__ _Float16 hbuf[2][4 * 144]; // h rows (batch 0..3), stride 144:
                                          // af reads worst-case 2-way (free),
                                          // measured 0 conflicts (r4/r5).

    // Register-resident W fragments, col = g*128 + u, scale prefolded.
    //   bfr_x[g][ks]: k = ks*32 + q*8 + j        (rows 0..127  = Wx)
    //   bfr_h[g][ks]: k = 128 + ks*32 + q*8 + j  (rows 128..255 = Wh)
    half8_t bfr_x[4][4], bfr_h[4][4];
    float sb[4];
#pragma unroll
    for (int g = 0; g < 4; ++g) {
        const float sc = (g == 1) ? (2.0f * KLOG2E) : (-KLOG2E);
#pragma unroll
        for (int ks = 0; ks < 4; ++ks) {
            const int col = g * 128 + u;
            const int kbx = ks * 32 + q * 8;
            half8_t fx, fh;
#pragma unroll
            for (int j = 0; j < 8; ++j) {
                fx[j] = (_Float16)(sc * Wd[(size_t)(kbx + j) * GDIM + col]);
                fh[j] = (_Float16)(sc * Wd[(size_t)(128 + kbx + j) * GDIM + col]);
            }
            bfr_x[g][ks] = fx;
            bfr_h[g][ks] = fh;
        }
        sb[g] = sc * (bd[g * 128 + u] + ((g == 2) ? 1.0f : 0.0f));
    }

    for (int i = tid; i < 2 * 4 * 144; i += 512) ((_Float16*)hbuf)[i] = (_Float16)0.f;

    // x A-fragment source: row = lm -> batch m = lm>>2, t_off r = lm&3.
    // Per-lane base covers (batch row, +-t_off, k = q*8); uniform tb*128 added
    // per burst. Backward direction uses t = tb - r.
    const int tsign = d ? -1 : 1;
    const float* xbase = x + (size_t)(b0 + (lm >> 2)) * (T_SEQ * 128)
                         + tsign * (lm & 3) * 128 + q * 8;
    const unsigned obase = (unsigned)((b0 + q) * T_SEQ) * 256u
                           + (unsigned)(d * 128 + u);

    // x prefetch for burst at s=0
    float4 px[8];
    {
        const float* xr = xbase + (size_t)(d ? (T_SEQ - 1) : 0) * 128;
#pragma unroll
        for (int ks = 0; ks < 4; ++ks) {
            px[ks * 2]     = *(const float4*)(xr + ks * 32);
            px[ks * 2 + 1] = *(const float4*)(xr + ks * 32 + 4);
        }
    }
    float cst = 0.f;
    __syncthreads();

#define REC_STEP(RD, WR, R, SCUR)                                             \
    {                                                                         \
        const int t_ = d ? (T_SEQ - 1 - (SCUR)) : (SCUR);                     \
        half8_t af[4];                                                        \
        _Pragma("unroll")                                                     \
        for (int ks = 0; ks < 4; ++ks)                                        \
            af[ks] = *(const half8_t*)&hbuf[RD][(lm & 3) * 144 + ks * 32 + q * 8]; \
        floatx4 acg[4];                                                       \
        _Pragma("unroll")                                                     \
        for (int g = 0; g < 4; ++g) acg[g] = (floatx4){0.f, 0.f, 0.f, 0.f};   \
        _Pragma("unroll")                                                     \
        for (int ks = 0; ks < 4; ++ks)                                        \
            _Pragma("unroll")                                                 \
            for (int g = 0; g < 4; ++g)                                       \
                acg[g] = __builtin_amdgcn_mfma_f32_16x16x32_f16(af[ks], bfr_h[g][ks], acg[g], 0, 0, 0); \
        float zi = zcs[0][R] + sel4(acg[0], q);                               \
        float zj = zcs[1][R] + sel4(acg[1], q);                               \
        float zf = zcs[2][R] + sel4(acg[2], q);                               \
        float zo = zcs[3][R] + sel4(acg[3], q);                               \
        cst = cst * sigm2(zf) + sigm2(zi) * tanh2(zj);                        \
        float hv = sigm2(zo) * tanh2(2.0f * KLOG2E * cst);                    \
        hbuf[WR][q * 144 + u] = (_Float16)hv;                                 \
        out[(size_t)t_ * 256 + obase] = hv;                                   \
        __builtin_amdgcn_sched_barrier(0);                                    \
        asm volatile("s_waitcnt lgkmcnt(0)");                                 \
        __builtin_amdgcn_s_barrier();                                         \
        __builtin_amdgcn_sched_barrier(0);                                    \
    }

    floatx4 zcs[4];
    for (int s = 0; s < T_SEQ; s += 4) {
        // ---- x-burst: zx for steps s..s+3, all in-register ----
        half8_t axf[4];
#pragma unroll
        for (int ks = 0; ks < 4; ++ks) {
            float4 a_ = px[ks * 2], b_ = px[ks * 2 + 1];
            half8_t f_;
            f_[0] = (_Float16)a_.x; f_[1] = (_Float16)a_.y;
            f_[2] = (_Float16)a_.z; f_[3] = (_Float16)a_.w;
            f_[4] = (_Float16)b_.x; f_[5] = (_Float16)b_.y;
            f_[6] = (_Float16)b_.z; f_[7] = (_Float16)b_.w;
            axf[ks] = f_;
        }
        {   // issue prefetch for next burst (4 steps of latency cover)
            int sn = s + 4; if (sn >= T_SEQ) sn = 0;   // dummy (valid) reload
            const int tbn = d ? (T_SEQ - 1 - sn) : sn;
            const float* xr = xbase + (size_t)tbn * 128;
#pragma unroll
            for (int ks = 0; ks < 4; ++ks) {
                px[ks * 2]     = *(const float4*)(xr + ks * 32);
                px[ks * 2 + 1] = *(const float4*)(xr + ks * 32 + 4);
            }
        }
#pragma unroll
        for (int g = 0; g < 4; ++g)
            zcs[g] = (floatx4){sb[g], sb[g], sb[g], sb[g]};
#pragma unroll
        for (int ks = 0; ks < 4; ++ks)
#pragma unroll
            for (int g = 0; g < 4; ++g)
                zcs[g] = __builtin_amdgcn_mfma_f32_16x16x32_f16(axf[ks], bfr_x[g][ks], zcs[g], 0, 0, 0);

        REC_STEP(0, 1, 0, s)
        REC_STEP(1, 0, 1, s + 1)
        REC_STEP(0, 1, 2, s + 2)
        REC_STEP(1, 0, 3, s + 3)
    }
#undef REC_STEP
}

extern "C" void kernel_launch(void* const* d_in, const int* in_sizes, int n_in,
                              void* d_out, int out_size, void* d_ws, size_t ws_size,
                              hipStream_t stream) {
    const float* x   = (const float*)d_in[0];
    const float* Wfw = (const float*)d_in[1];
    const float* bfw = (const float*)d_in[2];
    const float* Wbw = (const float*)d_in[3];
    const float* bbw = (const float*)d_in[4];
    float* out = (float*)d_out;
    (void)d_ws; (void)ws_size;

    dim3 g(16, 2);
    lstm_fused<<<g, 512, 0, stream>>>(x, Wfw, bfw, Wbw, bbw, out);
}

// Round 10
// 1238.468 us; speedup vs baseline: 1.8106x; 1.0174x over previous
//
#include <hip/hip_runtime.h>
#include <hip/hip_bf16.h>

// BiLSTM: B=64, T=2048, F=128, U=128. fp32 in/out. SINGLE FUSED KERNEL.
// 32 WGs (2 dir x 16 batch-groups of 4), 8 waves (2/SIMD - verified best),
// 1 cell/lane (batch q, unit u = w*16+lm).
// x-burst every 4 steps: 16 MFMAs compute z_x for steps s..s+3 into zcs;
// A-rows (both burst and rec) use row -> batch = row>>2, t_off/replica =
// row&3, so lane (q,lm)'s C/D regs are ALL batch q: reg R of the rec MFMA
// (C-init = zcs) is directly z_x(s+R) + z_h -> no sel4, no post-add, no
// acc zero-init. Wx/Wh register-resident with per-gate exp2 scales
// {-K, 2K, -K, -K} prefolded; bias prefolded into burst C-init. h stride
// 144 (0 conflicts measured), lgkm-only barrier (no "memory" clobber)
// keeps x prefetch + out stores in flight. Loop-carried out/x pointers.

typedef _Float16 half8_t __attribute__((ext_vector_type(8)));
typedef __fp16 fp16x2_t __attribute__((ext_vector_type(2)));  // cvt_pkrtz ret type
typedef float floatx4 __attribute__((ext_vector_type(4)));

#define T_SEQ 2048
#define GDIM 512
#define KLOG2E 1.4426950408889634f

__device__ __forceinline__ float exp2_f(float x) {
#if __has_builtin(__builtin_amdgcn_exp2f)
    return __builtin_amdgcn_exp2f(x);
#else
    return __expf(x * 0.6931471805599453f);
#endif
}
// sigmoid with pre-negated/scaled arg: x' = -K*x  =>  s = 1/(1+2^x')
__device__ __forceinline__ float sigm2(float x) {
    return __builtin_amdgcn_rcpf(1.0f + exp2_f(x));
}
// tanh with pre-scaled arg: x' = 2K*x  =>  t = 1 - 2/(1+2^x')
__device__ __forceinline__ float tanh2(float x) {
    return 1.0f - 2.0f * __builtin_amdgcn_rcpf(1.0f + exp2_f(x));
}

// grid: (16 batch-groups, 2 dirs), block 512 (8 waves, 2/SIMD).
__global__ __launch_bounds__(512, 2) void lstm_fused(
    const float* __restrict__ x,
    const float* __restrict__ Wfw, const float* __restrict__ bfw,
    const float* __restrict__ Wbw, const float* __restrict__ bbw,
    float* __restrict__ out) {
    const int bg = blockIdx.x;            // 0..15
    const int d = blockIdx.y;             // 0..1
    const int b0 = bg * 4;
    const float* Wd = d ? Wbw : Wfw;
    const float* bd = d ? bbw : bfw;
    const int tid = threadIdx.x;
    const int w = tid >> 6, lane = tid & 63, lm = lane & 15, q = lane >> 4;
    const int u = w * 16 + lm;            // unit 0..127; cell = (batch q, unit u)

    __shared__ _Float16 hbuf[2][4 * 144]; // h rows (batch 0..3), stride 144:
                                          // af reads worst-case 2-way (free),
                                          // measured 0 conflicts (r4/r5).

    // Register-resident W fragments, col = g*128 + u, scale prefolded.
    //   bfr_x[g][ks]: k = ks*32 + q*8 + j        (rows 0..127  = Wx)
    //   bfr_h[g][ks]: k = 128 + ks*32 + q*8 + j  (rows 128..255 = Wh)
    half8_t bfr_x[4][4], bfr_h[4][4];
    float sb[4];
#pragma unroll
    for (int g = 0; g < 4; ++g) {
        const float sc = (g == 1) ? (2.0f * KLOG2E) : (-KLOG2E);
#pragma unroll
        for (int ks = 0; ks < 4; ++ks) {
            const int col = g * 128 + u;
            const int kbx = ks * 32 + q * 8;
            half8_t fx, fh;
#pragma unroll
            for (int j = 0; j < 8; ++j) {
                fx[j] = (_Float16)(sc * Wd[(size_t)(kbx + j) * GDIM + col]);
                fh[j] = (_Float16)(sc * Wd[(size_t)(128 + kbx + j) * GDIM + col]);
            }
            bfr_x[g][ks] = fx;
            bfr_h[g][ks] = fh;
        }
        sb[g] = sc * (bd[g * 128 + u] + ((g == 2) ? 1.0f : 0.0f));
    }

    for (int i = tid; i < 2 * 4 * 144; i += 512) ((_Float16*)hbuf)[i] = (_Float16)0.f;

    // x A-fragment source: row = lm -> batch = lm>>2, t_off = lm&3.
    const int tsign = d ? -1 : 1;
    const int t0 = d ? (T_SEQ - 1) : 0;
    const float* xbase = x + (size_t)(b0 + (lm >> 2)) * (T_SEQ * 128)
                         + tsign * (lm & 3) * 128 + q * 8;
    const unsigned obase = (unsigned)((b0 + q) * T_SEQ) * 256u
                           + (unsigned)(d * 128 + u);
    float* orow = out + (size_t)t0 * 256;  // uniform part; advanced per step
    const int ostep = tsign * 256;

    // x prefetch, loop-carried per-lane pointer (advances one burst = 4 rows)
    const float* xp_next = xbase + (size_t)t0 * 128;
    float4 px[8];
#pragma unroll
    for (int ks = 0; ks < 4; ++ks) {
        px[ks * 2]     = *(const float4*)(xp_next + ks * 32);
        px[ks * 2 + 1] = *(const float4*)(xp_next + ks * 32 + 4);
    }
    xp_next += tsign * (4 * 128);

    float cst = 0.f;
    __syncthreads();

#define REC_STEP(RD, WR, R)                                                   \
    {                                                                         \
        half8_t af[4];                                                        \
        _Pragma("unroll")                                                     \
        for (int ks = 0; ks < 4; ++ks)                                        \
            af[ks] = *(const half8_t*)&hbuf[RD][(lm >> 2) * 144 + ks * 32 + q * 8]; \
        floatx4 acg[4];                                                       \
        _Pragma("unroll")                                                     \
        for (int g = 0; g < 4; ++g) acg[g] = zcs[g];                          \
        _Pragma("unroll")                                                     \
        for (int ks = 0; ks < 4; ++ks)                                        \
            _Pragma("unroll")                                                 \
            for (int g = 0; g < 4; ++g)                                       \
                acg[g] = __builtin_amdgcn_mfma_f32_16x16x32_f16(af[ks], bfr_h[g][ks], acg[g], 0, 0, 0); \
        float zi = acg[0][R], zj = acg[1][R], zf = acg[2][R], zo = acg[3][R]; \
        cst = cst * sigm2(zf) + sigm2(zi) * tanh2(zj);                        \
        float hv = sigm2(zo) * tanh2(2.0f * KLOG2E * cst);                    \
        hbuf[WR][q * 144 + u] = (_Float16)hv;                                 \
        orow[obase] = hv;                                                     \
        orow += ostep;                                                        \
        __builtin_amdgcn_sched_barrier(0);                                    \
        asm volatile("s_waitcnt lgkmcnt(0)");                                 \
        __builtin_amdgcn_s_barrier();                                         \
        __builtin_amdgcn_sched_barrier(0);                                    \
    }

    floatx4 zcs[4];
    for (int s = 0; s < T_SEQ; s += 4) {
        // ---- x-burst: zcs[g][j] = z_x(step s+j) for this lane's cell ----
        half8_t axf[4];
#pragma unroll
        for (int ks = 0; ks < 4; ++ks) {
            float4 a_ = px[ks * 2], b_ = px[ks * 2 + 1];
            union { fp16x2_t h2[4]; half8_t h8; } uu;
            uu.h2[0] = __builtin_amdgcn_cvt_pkrtz(a_.x, a_.y);
            uu.h2[1] = __builtin_amdgcn_cvt_pkrtz(a_.z, a_.w);
            uu.h2[2] = __builtin_amdgcn_cvt_pkrtz(b_.x, b_.y);
            uu.h2[3] = __builtin_amdgcn_cvt_pkrtz(b_.z, b_.w);
            axf[ks] = uu.h8;
        }
        if (s + 4 < T_SEQ) {  // uniform branch; skip dead prefetch on last burst
#pragma unroll
            for (int ks = 0; ks < 4; ++ks) {
                px[ks * 2]     = *(const float4*)(xp_next + ks * 32);
                px[ks * 2 + 1] = *(const float4*)(xp_next + ks * 32 + 4);
            }
            xp_next += tsign * (4 * 128);
        }
#pragma unroll
        for (int g = 0; g < 4; ++g)
            zcs[g] = (floatx4){sb[g], sb[g], sb[g], sb[g]};
#pragma unroll
        for (int ks = 0; ks < 4; ++ks)
#pragma unroll
            for (int g = 0; g < 4; ++g)
                zcs[g] = __builtin_amdgcn_mfma_f32_16x16x32_f16(axf[ks], bfr_x[g][ks], zcs[g], 0, 0, 0);

        REC_STEP(0, 1, 0)
        REC_STEP(1, 0, 1)
        REC_STEP(0, 1, 2)
        REC_STEP(1, 0, 3)
    }
#undef REC_STEP
}

extern "C" void kernel_launch(void* const* d_in, const int* in_sizes, int n_in,
                              void* d_out, int out_size, void* d_ws, size_t ws_size,
                              hipStream_t stream) {
    const float* x   = (const float*)d_in[0];
    const float* Wfw = (const float*)d_in[1];
    const float* bfw = (const float*)d_in[2];
    const float* Wbw = (const float*)d_in[3];
    const float* bbw = (const float*)d_in[4];
    float* out = (float*)d_out;
    (void)d_ws; (void)ws_size;

    dim3 g(16, 2);
    lstm_fused<<<g, 512, 0, stream>>>(x, Wfw, bfw, Wbw, bbw, out);
}

// Round 12
// 1224.565 us; speedup vs baseline: 1.8311x; 1.0114x over previous
//
#include <hip/hip_runtime.h>
#include <hip/hip_bf16.h>

// BiLSTM: B=64, T=2048, F=128, U=128. fp32 in/out. SINGLE FUSED KERNEL.
// 32 WGs (2 dir x 16 batch-groups of 4), 8 waves (2/SIMD - verified best),
// 1 cell/lane (batch q, unit u = w*16+lm).
// x-burst every 4 steps: 16 MFMAs compute z_x for steps s..s+3 into zcs;
// A-rows use row -> batch = row>>2, so lane (q,lm)'s C/D regs are ALL
// batch q: reg R of the rec MFMA (first ks consumes zcs as C directly -
// no copy) is z_x(s+R) + z_h. Wx/Wh register-resident with per-gate exp2
// scales {-K, 2K, -K, -K} prefolded; bias prefolded into burst C-init.
// cst register carries the 2K tanh pre-scale so the loop-carried chain has
// no rescale mul. s_setprio(1) around MFMA+gates (2 waves/SIMD skewed by
// the LDS queue -> priority arbitration pays). h stride 144 (verified 0
// conflicts), lgkm-only barrier (no "memory" clobber) keeps x prefetch +
// out stores in flight. Loop-carried out/x pointers.

typedef _Float16 half8_t __attribute__((ext_vector_type(8)));
typedef __fp16 fp16x2_t __attribute__((ext_vector_type(2)));  // cvt_pkrtz ret type
typedef float floatx4 __attribute__((ext_vector_type(4)));

#define T_SEQ 2048
#define GDIM 512
#define KLOG2E 1.4426950408889634f

__device__ __forceinline__ float exp2_f(float x) {
#if __has_builtin(__builtin_amdgcn_exp2f)
    return __builtin_amdgcn_exp2f(x);
#else
    return __expf(x * 0.6931471805599453f);
#endif
}
// sigmoid with pre-negated/scaled arg: x' = -K*x  =>  s = 1/(1+2^x')
__device__ __forceinline__ float sigm2(float x) {
    return __builtin_amdgcn_rcpf(1.0f + exp2_f(x));
}
// tanh with pre-scaled arg: x' = 2K*x  =>  t = 1 - 2/(1+2^x')
__device__ __forceinline__ float tanh2(float x) {
    return 1.0f - 2.0f * __builtin_amdgcn_rcpf(1.0f + exp2_f(x));
}

// grid: (16 batch-groups, 2 dirs), block 512 (8 waves, 2/SIMD).
__global__ __launch_bounds__(512, 2) void lstm_fused(
    const float* __restrict__ x,
    const float* __restrict__ Wfw, const float* __restrict__ bfw,
    const float* __restrict__ Wbw, const float* __restrict__ bbw,
    float* __restrict__ out) {
    const int bg = blockIdx.x;            // 0..15
    const int d = blockIdx.y;             // 0..1
    const int b0 = bg * 4;
    const float* Wd = d ? Wbw : Wfw;
    const float* bd = d ? bbw : bfw;
    const int tid = threadIdx.x;
    const int w = tid >> 6, lane = tid & 63, lm = lane & 15, q = lane >> 4;
    const int u = w * 16 + lm;            // unit 0..127; cell = (batch q, unit u)

    __shared__ _Float16 hbuf[2][4 * 144]; // h rows (batch 0..3), stride 144:
                                          // af reads worst-case 2-way (free),
                                          // measured 0 conflicts (r4/r5).

    // Register-resident W fragments, col = g*128 + u, scale prefolded.
    //   bfr_x[g][ks]: k = ks*32 + q*8 + j        (rows 0..127  = Wx)
    //   bfr_h[g][ks]: k = 128 + ks*32 + q*8 + j  (rows 128..255 = Wh)
    half8_t bfr_x[4][4], bfr_h[4][4];
    float sb[4];
#pragma unroll
    for (int g = 0; g < 4; ++g) {
        const float sc = (g == 1) ? (2.0f * KLOG2E) : (-KLOG2E);
#pragma unroll
        for (int ks = 0; ks < 4; ++ks) {
            const int col = g * 128 + u;
            const int kbx = ks * 32 + q * 8;
            half8_t fx, fh;
#pragma unroll
            for (int j = 0; j < 8; ++j) {
                fx[j] = (_Float16)(sc * Wd[(size_t)(kbx + j) * GDIM + col]);
                fh[j] = (_Float16)(sc * Wd[(size_t)(128 + kbx + j) * GDIM + col]);
            }
            bfr_x[g][ks] = fx;
            bfr_h[g][ks] = fh;
        }
        sb[g] = sc * (bd[g * 128 + u] + ((g == 2) ? 1.0f : 0.0f));
    }

    for (int i = tid; i < 2 * 4 * 144; i += 512) ((_Float16*)hbuf)[i] = (_Float16)0.f;

    // x A-fragment source: row = lm -> batch = lm>>2, t_off = lm&3.
    const int tsign = d ? -1 : 1;
    const int t0 = d ? (T_SEQ - 1) : 0;
    const float* xbase = x + (size_t)(b0 + (lm >> 2)) * (T_SEQ * 128)
                         + tsign * (lm & 3) * 128 + q * 8;
    const unsigned obase = (unsigned)((b0 + q) * T_SEQ) * 256u
                           + (unsigned)(d * 128 + u);
    float* orow = out + (size_t)t0 * 256;  // uniform part; advanced per step
    const int ostep = tsign * 256;

    // x prefetch, loop-carried per-lane pointer (advances one burst = 4 rows)
    const float* xp_next = xbase + (size_t)t0 * 128;
    float4 px[8];
#pragma unroll
    for (int ks = 0; ks < 4; ++ks) {
        px[ks * 2]     = *(const float4*)(xp_next + ks * 32);
        px[ks * 2 + 1] = *(const float4*)(xp_next + ks * 32 + 4);
    }
    xp_next += tsign * (4 * 128);

    float cst = 0.f;   // carries 2K*c (tanh2 pre-scale folded into the state)
    __syncthreads();

#define REC_STEP(RD, WR, R)                                                   \
    {                                                                         \
        half8_t af[4];                                                        \
        _Pragma("unroll")                                                     \
        for (int ks = 0; ks < 4; ++ks)                                        \
            af[ks] = *(const half8_t*)&hbuf[RD][(lm >> 2) * 144 + ks * 32 + q * 8]; \
        __builtin_amdgcn_s_setprio(1);                                        \
        floatx4 acg[4];                                                       \
        _Pragma("unroll")                                                     \
        for (int g = 0; g < 4; ++g)  /* first ks: C = zcs directly (no copy) */ \
            acg[g] = __builtin_amdgcn_mfma_f32_16x16x32_f16(af[0], bfr_h[g][0], zcs[g], 0, 0, 0); \
        _Pragma("unroll")                                                     \
        for (int ks = 1; ks < 4; ++ks)                                        \
            _Pragma("unroll")                                                 \
            for (int g = 0; g < 4; ++g)                                       \
                acg[g] = __builtin_amdgcn_mfma_f32_16x16x32_f16(af[ks], bfr_h[g][ks], acg[g], 0, 0, 0); \
        float zi = acg[0][R], zj = acg[1][R], zf = acg[2][R], zo = acg[3][R]; \
        /* cst carries 2K*c: rescale lands on the independent product term */ \
        cst = cst * sigm2(zf) + (2.0f * KLOG2E) * (sigm2(zi) * tanh2(zj));    \
        float hv = sigm2(zo) * tanh2(cst);                                    \
        __builtin_amdgcn_s_setprio(0);                                        \
        hbuf[WR][q * 144 + u] = (_Float16)hv;                                 \
        orow[obase] = hv;                                                     \
        orow += ostep;                                                        \
        __builtin_amdgcn_sched_barrier(0);                                    \
        asm volatile("s_waitcnt lgkmcnt(0)");                                 \
        __builtin_amdgcn_s_barrier();                                         \
        __builtin_amdgcn_sched_barrier(0);                                    \
    }

    floatx4 zcs[4];
    for (int s = 0; s < T_SEQ; s += 4) {
        // ---- x-burst: zcs[g][j] = z_x(step s+j) for this lane's cell ----
        half8_t axf[4];
#pragma unroll
        for (int ks = 0; ks < 4; ++ks) {
            float4 a_ = px[ks * 2], b_ = px[ks * 2 + 1];
            union { fp16x2_t h2[4]; half8_t h8; } uu;
            uu.h2[0] = __builtin_amdgcn_cvt_pkrtz(a_.x, a_.y);
            uu.h2[1] = __builtin_amdgcn_cvt_pkrtz(a_.z, a_.w);
            uu.h2[2] = __builtin_amdgcn_cvt_pkrtz(b_.x, b_.y);
            uu.h2[3] = __builtin_amdgcn_cvt_pkrtz(b_.z, b_.w);
            axf[ks] = uu.h8;
        }
        if (s + 4 < T_SEQ) {  // uniform branch; skip dead prefetch on last burst
#pragma unroll
            for (int ks = 0; ks < 4; ++ks) {
                px[ks * 2]     = *(const float4*)(xp_next + ks * 32);
                px[ks * 2 + 1] = *(const float4*)(xp_next + ks * 32 + 4);
            }
            xp_next += tsign * (4 * 128);
        }
#pragma unroll
        for (int g = 0; g < 4; ++g)
            zcs[g] = (floatx4){sb[g], sb[g], sb[g], sb[g]};
#pragma unroll
        for (int ks = 0; ks < 4; ++ks)
#pragma unroll
            for (int g = 0; g < 4; ++g)
                zcs[g] = __builtin_amdgcn_mfma_f32_16x16x32_f16(axf[ks], bfr_x[g][ks], zcs[g], 0, 0, 0);

        REC_STEP(0, 1, 0)
        REC_STEP(1, 0, 1)
        REC_STEP(0, 1, 2)
        REC_STEP(1, 0, 3)
    }
#undef REC_STEP
}

extern "C" void kernel_launch(void* const* d_in, const int* in_sizes, int n_in,
                              void* d_out, int out_size, void* d_ws, size_t ws_size,
                              hipStream_t stream) {
    const float* x   = (const float*)d_in[0];
    const float* Wfw = (const float*)d_in[1];
    const float* bfw = (const float*)d_in[2];
    const float* Wbw = (const float*)d_in[3];
    const float* bbw = (const float*)d_in[4];
    float* out = (float*)d_out;
    (void)d_ws; (void)ws_size;

    dim3 g(16, 2);
    lstm_fused<<<g, 512, 0, stream>>>(x, Wfw, bfw, Wbw, bbw, out);
}